// Round 26
// baseline (252.611 us; speedup 1.0000x reference)
//
#include <hip/hip_runtime.h>
#include <hip/hip_bf16.h>

// RGCN encoder: N=20000 nodes, E=640000 edges, F=64, H=128, L=2 layers,
// D=3 edge-attr dims, R=8 relations, block-diag B=4 blocks of c=32.
//
// R26 = R24 (verified, 249.5 us). R25's mask-hoist failed correctness by an
// inspection-resistant margin; restored to the proven kernel. Structure:
// fixed-slot CSR, inline ballot-indicator MFMA aggregation with permuted
// fragment channels (uint2 gathers), fused transform+root MFMA, bf16 h.

constexpr int H  = 128;
constexpr int F  = 64;
constexpr int D  = 3;
constexpr int R  = 8;
constexpr int CB = 32;      // block-diag block size
constexpr int CAP = 64;     // fast-path max degree (ballot width)
constexpr int CAPS = 96;    // fixed slots per node in elist
constexpr int ROWS = 8;     // gemm_h0

typedef __attribute__((ext_vector_type(8))) short short8v;
typedef __attribute__((ext_vector_type(4))) float f32x4;

template <int V> struct IC { static constexpr int value = V; };

__device__ __forceinline__ float b2f(unsigned short u) {
  return __uint_as_float(((unsigned)u) << 16);
}
__device__ __forceinline__ unsigned short f2b(float f) {
  __hip_bfloat16 h = __float2bfloat16(f);
  unsigned short u; __builtin_memcpy(&u, &h, 2); return u;
}
__device__ __forceinline__ unsigned packbf(float a, float b) {
  __hip_bfloat162 h2 = __float22bfloat162_rn(make_float2(a, b));
  unsigned u; __builtin_memcpy(&u, &h2, 4); return u;
}
__device__ __forceinline__ short8v mk8(unsigned w0, unsigned w1,
                                       unsigned w2, unsigned w3) {
  union { unsigned u[4]; short8v v; } c;
  c.u[0] = w0; c.u[1] = w1; c.u[2] = w2; c.u[3] = w3;
  return c.v;
}

// ---------------- fixed-slot CSR build ----------------

__global__ void fill_edges_fixed(const int* __restrict__ ei, const int* __restrict__ attr,
                                 int* __restrict__ cnt, unsigned* __restrict__ elist, int E) {
  int e = blockIdx.x * 256 + threadIdx.x;
  if (e >= E) return;
  int src = ei[e];
  int dst = ei[E + e];
  unsigned r0 = attr[e * D + 0], r1 = attr[e * D + 1], r2 = attr[e * D + 2];
  int p = atomicAdd(&cnt[dst], 1);
  if (p < CAPS)
    elist[(size_t)dst * CAPS + p] = (unsigned)src | (r0 << 16) | (r1 << 20) | (r2 << 24);
}

// ---------------- fused fragment prep (W + root, both layers) --------------

__global__ void prep_frags(const float* __restrict__ cw, const float* __restrict__ cr,
                           unsigned* __restrict__ Wf0, unsigned* __restrict__ Wf1,
                           unsigned* __restrict__ Rf0, unsigned* __restrict__ Rf1) {
  const int bid = blockIdx.x;
  const int b = threadIdx.x >> 6;
  const int l = threadIdx.x & 63;
  const int lo = l & 15, hi = l >> 4;
  const size_t wstride = (size_t)D * R * 4 * CB * CB;

  if (bid < 2 * D * R) {
    const int layer = bid / (D * R);
    const int jr = bid % (D * R);
    const float* w = cw + (size_t)layer * wstride;
    unsigned* Wfrag = layer ? Wf1 : Wf0;
    #pragma unroll
    for (int nt = 0; nt < 2; ++nt) {
      unsigned* dst = Wfrag + ((((size_t)jr * 4 + b) * 2 + nt) * 64 + l) * 4;
      #pragma unroll
      for (int ii = 0; ii < 4; ++ii) {
        const int k0 = hi * 8 + 2 * ii;
        const int nc = nt * 16 + lo;
        float v0 = w[(((size_t)jr * 4 + b) * CB + (k0 + 0)) * CB + nc];
        float v1 = w[(((size_t)jr * 4 + b) * CB + (k0 + 1)) * CB + nc];
        dst[ii] = packbf(v0, v1);
      }
    }
  } else {
    const int idx = bid - 2 * D * R;
    const int layer = idx / D;
    const int j = idx % D;
    const float* root = cr + (size_t)layer * D * H * H;
    unsigned* Rf = layer ? Rf1 : Rf0;
    #pragma unroll
    for (int nt = 0; nt < 2; ++nt) {
      #pragma unroll
      for (int kt = 0; kt < 4; ++kt) {
        unsigned* dst = Rf + (((((size_t)j * 4 + b) * 2 + nt) * 4 + kt) * 64 + l) * 4;
        #pragma unroll
        for (int ii = 0; ii < 4; ++ii) {
          const int k0 = kt * 32 + hi * 8 + 2 * ii;
          const int nc = b * 32 + nt * 16 + lo;
          float v0 = root[((size_t)j * H + (k0 + 0)) * H + nc];
          float v1 = root[((size_t)j * H + (k0 + 1)) * H + nc];
          dst[ii] = packbf(v0, v1);
        }
      }
    }
  }
}

// ---------------- h0 = x @ emb (bf16 out) ----------------

__global__ __launch_bounds__(128) void gemm_h0(const float* __restrict__ x,
                                               const float* __restrict__ emb,
                                               unsigned short* __restrict__ h0b, int N) {
  __shared__ float xs[ROWS][F];
  int r0 = blockIdx.x * ROWS;
  for (int i = threadIdx.x; i < ROWS * F; i += 128)
    xs[i >> 6][i & 63] = x[(size_t)r0 * F + i];
  __syncthreads();
  int d = threadIdx.x;
  float acc[ROWS] = {};
  for (int k = 0; k < F; ++k) {
    float ev = emb[k * H + d];
    #pragma unroll
    for (int r = 0; r < ROWS; ++r) acc[r] = fmaf(xs[r][k], ev, acc[r]);
  }
  #pragma unroll
  for (int r = 0; r < ROWS; ++r) h0b[(size_t)(r0 + r) * H + d] = f2b(acc[r]);
}

// ---------------- agg_mfma: permuted-column direct-gather indicator MFMA ---
// Block = 128 threads (2 waves) per dst node; wave w owns physical channels
// [64w, 64w+64). Fragment t col lo = PHYSICAL channel w*64 + lo*4 + t, so
// one uint2 (8B) load per slot serves all four fragments. deg<=32 -> NKS=1.

__global__ __launch_bounds__(128) void agg_mfma(
    const unsigned short* __restrict__ hsrc, const int* __restrict__ cnt,
    const unsigned* __restrict__ elist, unsigned short* __restrict__ S16,
    int cbeg, int csize) {
  const int n = cbeg + blockIdx.x;
  const int d = threadIdx.x;
  const int w = d >> 6, l = d & 63;
  const int lo = l & 15, hi = l >> 4;
  __shared__ unsigned long long masks[D][8];
  __shared__ float sinvf[D][8];

  const int beg = n * CAPS;
  int deg = cnt[n];
  if (deg > CAPS) deg = CAPS;
  const int nn = n - cbeg;

  if (deg <= CAP) {
    const bool lv = (l < deg);
    const int my_e = lv ? (int)elist[beg + l] : 0;

    #pragma unroll
    for (int j = 0; j < D; ++j) {
      const int relj = lv ? ((my_e >> (16 + 4 * j)) & 7) : 99;
      #pragma unroll
      for (int r = 0; r < R; ++r) {
        const unsigned long long mask = __ballot(relj == r);
        if (l == r) {
          masks[j][r] = mask;
          const int c = (int)__popcll(mask);
          sinvf[j][r] = (c > 0) ? 1.f / (float)c : 0.f;
        }
      }
    }

    auto body = [&](auto nksc) {
      constexpr int NKS = decltype(nksc)::value;

      // ---- one uint2 load per needed slot (4 contiguous phys channels) ----
      const unsigned chboff = (unsigned)((w * 64 + lo * 4) * 2);
      const char* __restrict__ hbase = (const char*)hsrc;
      uint2 rv[NKS][8];
      #pragma unroll
      for (int ks = 0; ks < NKS; ++ks)
        #pragma unroll
        for (int ii = 0; ii < 8; ++ii) {
          const unsigned s =
              (unsigned)__builtin_amdgcn_ds_bpermute((ks * 32 + hi * 8 + ii) * 4, my_e) & 0xFFFFu;
          rv[ks][ii] = *(const uint2*)(hbase + ((size_t)s << 8) + chboff);
        }

      // ---- fragment words from register halves (slot pair, channel t) ----
      unsigned bfr[NKS][4][4];
      #pragma unroll
      for (int ks = 0; ks < NKS; ++ks)
        #pragma unroll
        for (int t = 0; t < 4; ++t)
          #pragma unroll
          for (int ii = 0; ii < 4; ++ii) {
            const unsigned a = (t & 2) ? rv[ks][2 * ii].y : rv[ks][2 * ii].x;
            const unsigned b2 = (t & 2) ? rv[ks][2 * ii + 1].y : rv[ks][2 * ii + 1].x;
            bfr[ks][t][ii] = (t & 1) ? ((a >> 16) | (b2 & 0xFFFF0000u))
                                     : ((a & 0xFFFFu) | (b2 << 16));
          }

      auto buildA = [&](unsigned long long mj, short8v* aV) {
        #pragma unroll
        for (int ks = 0; ks < NKS; ++ks) {
          const unsigned byte = (unsigned)((mj >> (ks * 32 + hi * 8)) & 0xFFull);
          unsigned aw[4];
          #pragma unroll
          for (int ii = 0; ii < 4; ++ii) {
            const unsigned b0 = (byte >> (2 * ii)) & 1u;
            const unsigned b1 = (byte >> (2 * ii + 1)) & 1u;
            aw[ii] = (b0 ? 0x3F80u : 0u) | (b1 ? 0x3F800000u : 0u);
          }
          aV[ks] = mk8(aw[0], aw[1], aw[2], aw[3]);
        }
      };
      auto runN = [&](const short8v* aV, f32x4& c0, f32x4& c1, f32x4& c2, f32x4& c3) {
        #pragma unroll
        for (int ks = 0; ks < NKS; ++ks) {
          c0 = __builtin_amdgcn_mfma_f32_16x16x32_bf16(aV[ks], mk8(bfr[ks][0][0], bfr[ks][0][1], bfr[ks][0][2], bfr[ks][0][3]), c0, 0, 0, 0);
          c1 = __builtin_amdgcn_mfma_f32_16x16x32_bf16(aV[ks], mk8(bfr[ks][1][0], bfr[ks][1][1], bfr[ks][1][2], bfr[ks][1][3]), c1, 0, 0, 0);
          c2 = __builtin_amdgcn_mfma_f32_16x16x32_bf16(aV[ks], mk8(bfr[ks][2][0], bfr[ks][2][1], bfr[ks][2][2], bfr[ks][2][3]), c2, 0, 0, 0);
          c3 = __builtin_amdgcn_mfma_f32_16x16x32_bf16(aV[ks], mk8(bfr[ks][3][0], bfr[ks][3][1], bfr[ks][3][2], bfr[ks][3][3]), c3, 0, 0, 0);
        }
      };

      // ---- pair (j0 rows 0-7, j1 rows 8-15); store un-permutes: ch=lo*4+t --
      {
        const unsigned long long mj = (lo < 8) ? masks[0][lo] : masks[1][lo & 7];
        short8v aV[NKS];
        buildA(mj, aV);
        f32x4 c0 = {0.f, 0.f, 0.f, 0.f}, c1 = {0.f, 0.f, 0.f, 0.f};
        f32x4 c2 = {0.f, 0.f, 0.f, 0.f}, c3 = {0.f, 0.f, 0.f, 0.f};
        runN(aV, c0, c1, c2, c3);
        #pragma unroll
        for (int q = 0; q < 4; ++q) {
          const int row = hi * 4 + q;
          const int jq = row >> 3;
          const int rr = row & 7;
          const float sv = sinvf[jq][rr];
          uint2 pk;
          pk.x = packbf(c0[q] * sv, c1[q] * sv);
          pk.y = packbf(c2[q] * sv, c3[q] * sv);
          *(uint2*)(S16 + ((size_t)(jq * R + rr) * csize + nn) * H + w * 64 + lo * 4) = pk;
        }
      }
      // ---- j2 (rows 0-7) ----
      {
        const unsigned long long mj = (lo < 8) ? masks[2][lo] : 0ull;
        short8v aV[NKS];
        buildA(mj, aV);
        f32x4 c0 = {0.f, 0.f, 0.f, 0.f}, c1 = {0.f, 0.f, 0.f, 0.f};
        f32x4 c2 = {0.f, 0.f, 0.f, 0.f}, c3 = {0.f, 0.f, 0.f, 0.f};
        runN(aV, c0, c1, c2, c3);
        if (hi < 2) {
          #pragma unroll
          for (int q = 0; q < 4; ++q) {
            const int rr = hi * 4 + q;
            const float sv = sinvf[2][rr];
            uint2 pk;
            pk.x = packbf(c0[q] * sv, c1[q] * sv);
            pk.y = packbf(c2[q] * sv, c3[q] * sv);
            *(uint2*)(S16 + ((size_t)(2 * R + rr) * csize + nn) * H + w * 64 + lo * 4) = pk;
          }
        }
      }
    };

    if (deg <= 32) body(IC<1>{});
    else           body(IC<2>{});
  } else {
    float s[D * R];
    int cl[D * R];
    #pragma unroll
    for (int k = 0; k < D * R; ++k) { s[k] = 0.f; cl[k] = 0; }
    const unsigned short* __restrict__ hd = hsrc + d;
    const int endp = beg + deg;
    for (int e = beg; e < endp; ++e) {
      const unsigned u = elist[e];
      const float v = b2f(hd[(size_t)(u & 0xFFFFu) * H]);
      #pragma unroll
      for (int j = 0; j < D; ++j) {
        const unsigned rel = (u >> (16 + 4 * j)) & 7u;
        #pragma unroll
        for (int r = 0; r < R; ++r) {
          s[j * R + r] += (rel == (unsigned)r) ? v : 0.f;
          cl[j * R + r] += (rel == (unsigned)r) ? 1 : 0;
        }
      }
    }
    #pragma unroll
    for (int k = 0; k < D * R; ++k) {
      const float mv = (cl[k] > 0) ? s[k] * (1.f / (float)cl[k]) : 0.f;
      S16[((size_t)k * csize + nn) * H + d] = f2b(mv);
    }
  }
}

// ---------------- fused transform + root + bias + relu ---------------------

__global__ __launch_bounds__(256) void fused_tm(
    const unsigned* __restrict__ Sbuf, const unsigned* __restrict__ Wfrag,
    const unsigned short* __restrict__ hb, const unsigned* __restrict__ Rf,
    const float* __restrict__ biasall,
    unsigned short* __restrict__ outb, float* __restrict__ outf,
    int cbeg, int csize, int N_all) {
  const int j = blockIdx.y;
  const int n0 = blockIdx.x * 32;
  const int gn0 = cbeg + n0;
  const int b = threadIdx.x >> 6;
  const int l = threadIdx.x & 63;
  const int lo = l & 15, hi = l >> 4;

  f32x4 acc00 = {0.f, 0.f, 0.f, 0.f};
  f32x4 acc01 = {0.f, 0.f, 0.f, 0.f};
  f32x4 acc10 = {0.f, 0.f, 0.f, 0.f};
  f32x4 acc11 = {0.f, 0.f, 0.f, 0.f};

  for (int r = 0; r < R; ++r) {
    const int jr = j * R + r;
    const short8v a0 = *(const short8v*)(Sbuf + ((size_t)jr * csize + n0 + lo) * 64 + b * 16 + hi * 4);
    const short8v a1 = *(const short8v*)(Sbuf + ((size_t)jr * csize + n0 + 16 + lo) * 64 + b * 16 + hi * 4);
    const short8v b0 = *(const short8v*)(Wfrag + ((((size_t)jr * 4 + b) * 2 + 0) * 64 + l) * 4);
    const short8v b1 = *(const short8v*)(Wfrag + ((((size_t)jr * 4 + b) * 2 + 1) * 64 + l) * 4);
    acc00 = __builtin_amdgcn_mfma_f32_16x16x32_bf16(a0, b0, acc00, 0, 0, 0);
    acc01 = __builtin_amdgcn_mfma_f32_16x16x32_bf16(a0, b1, acc01, 0, 0, 0);
    acc10 = __builtin_amdgcn_mfma_f32_16x16x32_bf16(a1, b0, acc10, 0, 0, 0);
    acc11 = __builtin_amdgcn_mfma_f32_16x16x32_bf16(a1, b1, acc11, 0, 0, 0);
  }

  #pragma unroll
  for (int kt = 0; kt < 4; ++kt) {
    const short8v a0 = *(const short8v*)&hb[(size_t)(gn0 + lo) * H + kt * 32 + hi * 8];
    const short8v a1 = *(const short8v*)&hb[(size_t)(gn0 + 16 + lo) * H + kt * 32 + hi * 8];
    const short8v b0 = *(const short8v*)&Rf[(((((size_t)j * 4 + b) * 2 + 0) * 4 + kt) * 64 + l) * 4];
    const short8v b1 = *(const short8v*)&Rf[(((((size_t)j * 4 + b) * 2 + 1) * 4 + kt) * 64 + l) * 4];
    acc00 = __builtin_amdgcn_mfma_f32_16x16x32_bf16(a0, b0, acc00, 0, 0, 0);
    acc01 = __builtin_amdgcn_mfma_f32_16x16x32_bf16(a0, b1, acc01, 0, 0, 0);
    acc10 = __builtin_amdgcn_mfma_f32_16x16x32_bf16(a1, b0, acc10, 0, 0, 0);
    acc11 = __builtin_amdgcn_mfma_f32_16x16x32_bf16(a1, b1, acc11, 0, 0, 0);
  }

  const int c0 = b * 32 + lo;
  const int c1 = c0 + 16;
  const float bias0 = biasall[j * H + c0];
  const float bias1 = biasall[j * H + c1];

  #pragma unroll
  for (int q = 0; q < 4; ++q) {
    const int row0 = gn0 + hi * 4 + q;
    const int row1 = row0 + 16;
    float v00 = fmaxf(acc00[q] + bias0, 0.f);
    float v01 = fmaxf(acc01[q] + bias1, 0.f);
    float v10 = fmaxf(acc10[q] + bias0, 0.f);
    float v11 = fmaxf(acc11[q] + bias1, 0.f);
    if (outb) {
      outb[((size_t)j * N_all + row0) * H + c0] = f2b(v00);
      outb[((size_t)j * N_all + row0) * H + c1] = f2b(v01);
      outb[((size_t)j * N_all + row1) * H + c0] = f2b(v10);
      outb[((size_t)j * N_all + row1) * H + c1] = f2b(v11);
    } else {
      outf[((size_t)j * N_all + row0) * H + c0] = v00;
      outf[((size_t)j * N_all + row0) * H + c1] = v01;
      outf[((size_t)j * N_all + row1) * H + c0] = v10;
      outf[((size_t)j * N_all + row1) * H + c1] = v11;
    }
  }
}

// ---------------- root-only matmul + bias + relu (layer-1 rows >= N) -------

__global__ __launch_bounds__(256) void matB_root(
    const unsigned short* __restrict__ hb, const unsigned* __restrict__ Rf,
    const float* __restrict__ biasall, float* __restrict__ outf,
    int n0base, int N_all) {
  const int j = blockIdx.y;
  const int n0 = n0base + blockIdx.x * 32;
  const int b = threadIdx.x >> 6;
  const int l = threadIdx.x & 63;
  const int lo = l & 15, hi = l >> 4;

  f32x4 acc00 = {0.f, 0.f, 0.f, 0.f};
  f32x4 acc01 = {0.f, 0.f, 0.f, 0.f};
  f32x4 acc10 = {0.f, 0.f, 0.f, 0.f};
  f32x4 acc11 = {0.f, 0.f, 0.f, 0.f};

  #pragma unroll
  for (int kt = 0; kt < 4; ++kt) {
    const short8v a0 = *(const short8v*)&hb[(size_t)(n0 + lo) * H + kt * 32 + hi * 8];
    const short8v a1 = *(const short8v*)&hb[(size_t)(n0 + 16 + lo) * H + kt * 32 + hi * 8];
    const short8v b0 = *(const short8v*)&Rf[(((((size_t)j * 4 + b) * 2 + 0) * 4 + kt) * 64 + l) * 4];
    const short8v b1 = *(const short8v*)&Rf[(((((size_t)j * 4 + b) * 2 + 1) * 4 + kt) * 64 + l) * 4];
    acc00 = __builtin_amdgcn_mfma_f32_16x16x32_bf16(a0, b0, acc00, 0, 0, 0);
    acc01 = __builtin_amdgcn_mfma_f32_16x16x32_bf16(a0, b1, acc01, 0, 0, 0);
    acc10 = __builtin_amdgcn_mfma_f32_16x16x32_bf16(a1, b0, acc10, 0, 0, 0);
    acc11 = __builtin_amdgcn_mfma_f32_16x16x32_bf16(a1, b1, acc11, 0, 0, 0);
  }

  const int c0 = b * 32 + lo;
  const int c1 = c0 + 16;
  const float bias0 = biasall[j * H + c0];
  const float bias1 = biasall[j * H + c1];

  #pragma unroll
  for (int q = 0; q < 4; ++q) {
    const int row0 = n0 + hi * 4 + q;
    const int row1 = row0 + 16;
    outf[((size_t)j * N_all + row0) * H + c0] = fmaxf(acc00[q] + bias0, 0.f);
    outf[((size_t)j * N_all + row0) * H + c1] = fmaxf(acc01[q] + bias1, 0.f);
    outf[((size_t)j * N_all + row1) * H + c0] = fmaxf(acc10[q] + bias0, 0.f);
    outf[((size_t)j * N_all + row1) * H + c1] = fmaxf(acc11[q] + bias1, 0.f);
  }
}

// ---------------- launch ----------------

extern "C" void kernel_launch(void* const* d_in, const int* in_sizes, int n_in,
                              void* d_out, int out_size, void* d_ws, size_t ws_size,
                              hipStream_t stream) {
  const float* x    = (const float*)d_in[0];
  const int*   ei   = (const int*)d_in[1];
  const int*   attr = (const int*)d_in[2];
  const float* emb  = (const float*)d_in[3];
  const float* cw   = (const float*)d_in[4];
  const float* cr   = (const float*)d_in[5];
  const float* cb   = (const float*)d_in[6];
  float* out = (float*)d_out;

  const int N = in_sizes[0] / F;   // 20000
  const int E = in_sizes[1] / 2;   // 640000

  char* ws = (char*)d_ws;
  size_t woff = 0;
  auto alloc = [&](size_t bytes) -> void* {
    void* p = ws + woff;
    woff = (woff + bytes + 255) & ~(size_t)255;
    return p;
  };
  unsigned short* h0b = (unsigned short*)alloc((size_t)N * H * 2);
  unsigned short* h1b = (unsigned short*)alloc((size_t)D * N * H * 2);
  int*      cnt     = (int*)alloc((size_t)N * 4);
  unsigned* elist   = (unsigned*)alloc((size_t)N * CAPS * 4);
  unsigned* Wfrag0  = (unsigned*)alloc((size_t)D * R * 4 * 2 * 64 * 4 * 4);
  unsigned* Wfrag1  = (unsigned*)alloc((size_t)D * R * 4 * 2 * 64 * 4 * 4);
  unsigned* Rfrag0  = (unsigned*)alloc((size_t)D * 4 * 2 * 4 * 64 * 4 * 4);
  unsigned* Rfrag1  = (unsigned*)alloc((size_t)D * 4 * 2 * 4 * 64 * 4 * 4);

  // runtime-sized S chunk: 6144 B per node (24 * 128 * 2B)
  const size_t perNode = (size_t)D * R * H * 2;
  int CHUNK = 32;
  if (ws_size > woff + 256) {
    size_t avail = ws_size - woff - 256;
    size_t c = avail / perNode;
    if (c > (size_t)N) c = N;
    CHUNK = (int)(c / 32) * 32;
    if (CHUNK < 32) CHUNK = 32;
  }
  unsigned* Sbuf = (unsigned*)alloc((size_t)CHUNK * perNode);

  hipMemsetAsync(cnt, 0, (size_t)N * 4, stream);
  fill_edges_fixed<<<(E + 255) / 256, 256, 0, stream>>>(ei, attr, cnt, elist, E);

  prep_frags<<<2 * D * R + 2 * D, 256, 0, stream>>>(cw, cr, Wfrag0, Wfrag1,
                                                    Rfrag0, Rfrag1);

  gemm_h0<<<N / ROWS, 128, 0, stream>>>(x, emb, h0b, N);

  for (int layer = 0; layer < 2; ++layer) {
    const unsigned short* h = (layer == 0) ? h0b : h1b;
    const unsigned* Wf = (layer == 0) ? Wfrag0 : Wfrag1;
    const unsigned* Rfr = (layer == 0) ? Rfrag0 : Rfrag1;
    const float* bias = cb + (size_t)layer * D * H;
    const int N_all = (layer == 0) ? N : D * N;
    for (int cbeg = 0; cbeg < N; cbeg += CHUNK) {
      const int csize = (N - cbeg < CHUNK) ? (N - cbeg) : CHUNK;
      agg_mfma<<<csize, 128, 0, stream>>>(h, cnt, elist,
                                          (unsigned short*)Sbuf, cbeg, csize);
      dim3 tg(csize / 32, D);
      if (layer == 0)
        fused_tm<<<tg, 256, 0, stream>>>(Sbuf, Wf, h0b, Rfr, bias,
                                         h1b, nullptr, cbeg, csize, N_all);
      else
        fused_tm<<<tg, 256, 0, stream>>>(Sbuf, Wf, h1b, Rfr, bias,
                                         nullptr, out, cbeg, csize, N_all);
    }
    if (layer == 1) {
      dim3 grid((D * N - N) / 32, D);
      matB_root<<<grid, 256, 0, stream>>>(h1b, Rfr, bias, out, N, N_all);
    }
  }
}